// Round 2
// baseline (152.510 us; speedup 1.0000x reference)
//
#include <hip/hip_runtime.h>
#include <math.h>

// VQC_Registers_BS_density: 16 layers of U rho U^T with U_l = G(th_l) (x) I
// (even l, row-register pairs) or I (x) G(th_l) (odd l, col-register pairs).
// G's 2x2 blocks M(th)=[[sin,cos],[-cos,sin]]=R(th-pi/2) are rotations on the
// SAME pair structure every layer with scalar angle per layer, so the product
// collapses exactly to (R(SA) (x) R(SB)) rho (R(SA) (x) R(SB))^T with
// SA = sum of even-layer angles, SB = sum of odd-layer angles
// (8 factors of -pi/2 = -4pi = identity rotation).
//
// Flat index of rho[s,t], s=r1*32+c1, t=r2*32+c2:
//   idx = r1*32768 + c1*1024 + r2*32 + c2
// Four independent 2-point butterflies along the low bit of each of r1
// (stride 32768), c1 (1024), r2 (32), c2 (1).
//
// Vectorized: each thread owns a float4 along c2 (two c2-butterfly groups)
// x the 2x2x2 (r1,c1,r2) partners = 8 float4 loads, 16 B/lane coalesced.
// 32768 threads = 256 blocks x 128 threads -> all 256 CUs, 2 waves/CU,
// 8 outstanding 1 KB wave-loads each (~16 KB/CU in flight, covers ~900 cyc
// HBM latency at ~10 B/cyc/CU).

__global__ __launch_bounds__(128) void vqc_bs_density_kernel(
    const float* __restrict__ rho,
    const float* __restrict__ angles,
    float* __restrict__ out) {

    // Composed angles (wave-uniform; 64 B array, L1-resident).
    float SA = 0.f, SB = 0.f;
#pragma unroll
    for (int l = 0; l < 16; l += 2) SA += angles[l];
#pragma unroll
    for (int l = 1; l < 16; l += 2) SB += angles[l];
    float ca, sa, cb, sb;
    sincosf(SA, &sa, &ca);
    sincosf(SB, &sb, &cb);

    const int gid = blockIdx.x * blockDim.x + threadIdx.x;  // 0..32767
    const int c2q = gid & 7;          // which float4 along c2 (32 floats / 4)
    const int r2g = (gid >> 3) & 15;  // r2 pair group
    const int c1g = (gid >> 7) & 15;  // c1 pair group
    const int r1g = (gid >> 11) & 15; // r1 pair group

    const int base = ((r1g * 2) * 32 + (c1g * 2)) * 1024 + (r2g * 2) * 32 + c2q * 4;

    // v[dr1][dc1][dr2] = float4 over 4 consecutive c2 (two dc2 pairs).
    float4 v[2][2][2];
#pragma unroll
    for (int dr1 = 0; dr1 < 2; ++dr1)
#pragma unroll
        for (int dc1 = 0; dc1 < 2; ++dc1)
#pragma unroll
            for (int dr2 = 0; dr2 < 2; ++dr2)
                v[dr1][dc1][dr2] =
                    *(const float4*)(rho + base + dr1 * 32768 + dc1 * 1024 + dr2 * 32);

    // Stage r1: rotation (ca,sa) mixing dr1.
#pragma unroll
    for (int dc1 = 0; dc1 < 2; ++dc1)
#pragma unroll
        for (int dr2 = 0; dr2 < 2; ++dr2) {
            const float4 e = v[0][dc1][dr2];
            const float4 o = v[1][dc1][dr2];
            v[0][dc1][dr2] = make_float4(ca * e.x - sa * o.x, ca * e.y - sa * o.y,
                                         ca * e.z - sa * o.z, ca * e.w - sa * o.w);
            v[1][dc1][dr2] = make_float4(sa * e.x + ca * o.x, sa * e.y + ca * o.y,
                                         sa * e.z + ca * o.z, sa * e.w + ca * o.w);
        }

    // Stage c1: rotation (cb,sb) mixing dc1.
#pragma unroll
    for (int dr1 = 0; dr1 < 2; ++dr1)
#pragma unroll
        for (int dr2 = 0; dr2 < 2; ++dr2) {
            const float4 e = v[dr1][0][dr2];
            const float4 o = v[dr1][1][dr2];
            v[dr1][0][dr2] = make_float4(cb * e.x - sb * o.x, cb * e.y - sb * o.y,
                                         cb * e.z - sb * o.z, cb * e.w - sb * o.w);
            v[dr1][1][dr2] = make_float4(sb * e.x + cb * o.x, sb * e.y + cb * o.y,
                                         sb * e.z + cb * o.z, sb * e.w + cb * o.w);
        }

    // Stage r2: rotation (ca,sa) mixing dr2.
#pragma unroll
    for (int dr1 = 0; dr1 < 2; ++dr1)
#pragma unroll
        for (int dc1 = 0; dc1 < 2; ++dc1) {
            const float4 e = v[dr1][dc1][0];
            const float4 o = v[dr1][dc1][1];
            v[dr1][dc1][0] = make_float4(ca * e.x - sa * o.x, ca * e.y - sa * o.y,
                                         ca * e.z - sa * o.z, ca * e.w - sa * o.w);
            v[dr1][dc1][1] = make_float4(sa * e.x + ca * o.x, sa * e.y + ca * o.y,
                                         sa * e.z + ca * o.z, sa * e.w + ca * o.w);
        }

    // Stage c2: rotation (cb,sb) mixing adjacent lanes inside each float4.
#pragma unroll
    for (int dr1 = 0; dr1 < 2; ++dr1)
#pragma unroll
        for (int dc1 = 0; dc1 < 2; ++dc1)
#pragma unroll
            for (int dr2 = 0; dr2 < 2; ++dr2) {
                const float4 t = v[dr1][dc1][dr2];
                v[dr1][dc1][dr2] = make_float4(cb * t.x - sb * t.y, sb * t.x + cb * t.y,
                                               cb * t.z - sb * t.w, sb * t.z + cb * t.w);
            }

    // Store.
#pragma unroll
    for (int dr1 = 0; dr1 < 2; ++dr1)
#pragma unroll
        for (int dc1 = 0; dc1 < 2; ++dc1)
#pragma unroll
            for (int dr2 = 0; dr2 < 2; ++dr2)
                *(float4*)(out + base + dr1 * 32768 + dc1 * 1024 + dr2 * 32) =
                    v[dr1][dc1][dr2];
}

extern "C" void kernel_launch(void* const* d_in, const int* in_sizes, int n_in,
                              void* d_out, int out_size, void* d_ws, size_t ws_size,
                              hipStream_t stream) {
    const float* rho = (const float*)d_in[0];     // input_state, 1024*1024 f32
    const float* angles = (const float*)d_in[1];  // 16 f32
    float* out = (float*)d_out;                   // 1024*1024 f32
    // 32768 threads: 256 blocks x 128 threads (2 waves/CU, 8x16B loads each).
    vqc_bs_density_kernel<<<256, 128, 0, stream>>>(rho, angles, out);
}